// Round 12
// baseline (2467.812 us; speedup 1.0000x reference)
//
#include <hip/hip_runtime.h>
#include <cstdint>
#include <cstddef>

typedef _Float16 f16;
typedef _Float16 f16x4 __attribute__((ext_vector_type(4)));
typedef _Float16 f16x8 __attribute__((ext_vector_type(8)));
typedef float f32x4 __attribute__((ext_vector_type(4)));
typedef float f32x16 __attribute__((ext_vector_type(16)));

// ---------- sizes ----------
#define SEQ 1024
#define BATCH 128
#define INDIM 256
#define HDIM 512
#define MROWS (SEQ * BATCH)          // 131072
#define NCOLS (3 * HDIM)             // 1536
#define BHDIM (BATCH * HDIM)         // 65536
#define TCHUNK 128
#define CHROWS (TCHUNK * BATCH)      // 16384

// workspace layout (bytes); total 506,730,496 (ws proven in [506.7MB, 538.4MB) — r0 vs r5 guards)
#define P32_OFF   0ull                         // [16384][1536] f32 = 100,663,296
#define XHI_OFF   100663296ull                 // [131072][256] f16 = 67,108,864
#define XLO_OFF   167772160ull                 // [131072][256] f16 = 67,108,864
#define Y0HI_OFF  234881024ull                 // [131072][512] f16 = 134,217,728
#define Y0LO_OFF  369098752ull                 // [131072][512] f16 = 134,217,728
#define WHI_OFF   503316480ull                 // [1536][512] f16   = 1,572,864
#define WLO_OFF   504889344ull                 // [1536][512] f16   = 1,572,864
#define BIAS_OFF  506462208ull                 // [1536] f32
#define HST_OFF   506468352ull                 // [65536] f32
#define WS_NEEDED 506730496ull

__device__ __forceinline__ float fast_tanh(float x) {
  return 1.0f - 2.0f / (__expf(2.0f * x) + 1.0f);
}
__device__ __forceinline__ float fast_sigmoid(float x) {
  return 1.0f / (1.0f + __expf(-x));
}

__device__ __forceinline__ void split4(const float* __restrict__ in, f16* __restrict__ hi,
                                       f16* __restrict__ lo, int i) {
  float4 v = reinterpret_cast<const float4*>(in)[i];
  f16x4 h4 = {(f16)v.x, (f16)v.y, (f16)v.z, (f16)v.w};
  f16x4 l4 = {(f16)((v.x - (float)h4[0]) * 2048.0f),
              (f16)((v.y - (float)h4[1]) * 2048.0f),
              (f16)((v.z - (float)h4[2]) * 2048.0f),
              (f16)((v.w - (float)h4[3]) * 2048.0f)};
  reinterpret_cast<f16x4*>(hi)[i] = h4;
  reinterpret_cast<f16x4*>(lo)[i] = l4;
}

// ---------- consolidated prep: x-split (optional) + 3 weight splits + 3 bias copies ----------
__global__ __launch_bounds__(256) void prep_kernel(
    const float* __restrict__ x, f16* __restrict__ xh, f16* __restrict__ xl, int n4x,
    const float* __restrict__ w0, const float* __restrict__ w1, const float* __restrict__ w2,
    f16* __restrict__ wh, f16* __restrict__ wl, int n4w,
    const float* __restrict__ b0, const float* __restrict__ b1, const float* __restrict__ b2,
    float* __restrict__ bias, int nb4) {
  const int total = n4x + 3 * n4w + 3 * nb4;
  const int stride = gridDim.x * blockDim.x;
  for (int i = blockIdx.x * blockDim.x + threadIdx.x; i < total; i += stride) {
    if (i < n4x) {
      split4(x, xh, xl, i);
    } else if (i < n4x + 3 * n4w) {
      int k = i - n4x;
      int m = k / n4w;
      int off = k - m * n4w;
      const float* src = (m == 0) ? w0 : ((m == 1) ? w1 : w2);
      split4(src, wh + (long)m * n4w * 4, wl + (long)m * n4w * 4, off);
    } else {
      int k = i - n4x - 3 * n4w;
      int m = k / nb4;
      int off = k - m * nb4;
      const float* src = (m == 0) ? b0 : ((m == 1) ? b1 : b2);
      reinterpret_cast<float4*>(bias)[m * nb4 + off] =
          reinterpret_cast<const float4*>(src)[off];
    }
  }
}

// ---------- GEMM: P[CHROWS,1536](f32) = (Ahi+Alo/2048).(Whi+Wlo/2048)^T + bias ----------
// r9 base (padded LDS, T14 reg-staged dbuf, 1 sync/K-step) with 32x32x16 MFMA:
// 24 MFMA/K-step/wave (vs 48), 2x FLOP each, ceiling 2382 vs 2075 TF. Per-ks frag reads
// cap live operand regs -> ~240 total -> 2 waves/SIMD via __launch_bounds__(256,2).
// A/B frag: row = lane&31, k = ks*16 + (lane>>5)*8 (generalizes verified 16x16 map).
// C/D (measured m74/m101): col = lane&31, row = (reg&3) + 8*(reg>>2) + 4*(lane>>5).
__global__ __launch_bounds__(256, 2) void gemm_split_kernel(
    const f16* __restrict__ Ahi, const f16* __restrict__ Alo,
    const f16* __restrict__ Whi, const f16* __restrict__ Wlo,
    const float* __restrict__ bias, float* __restrict__ P, int K) {
  constexpr int BK = 32;
  constexpr int LDSS = BK + 8;  // 40 f16 = 80 B row stride
  __shared__ f16 sAh[2][128 * LDSS];
  __shared__ f16 sAl[2][128 * LDSS];
  __shared__ f16 sBh[2][128 * LDSS];
  __shared__ f16 sBl[2][128 * LDSS];

  const int tid = threadIdx.x;
  const int lane = tid & 63;
  const int w = tid >> 6;
  const int wm = (w >> 1) * 64;
  const int wn = (w & 1) * 64;

  // XCD-aware bijective swizzle (gridDim.x = 1536, %8 == 0), n-block fastest
  const int per = gridDim.x >> 3;
  const int logical = (blockIdx.x & 7) * per + (blockIdx.x >> 3);
  const int nb = logical % (NCOLS / 128);
  const int mb = logical / (NCOLS / 128);
  const long m0 = (long)mb * 128;
  const int n0 = nb * 128;

  const int fr32 = lane & 31;
  const int fk32 = (lane >> 5) * 8;

  // staging indices (r2/r9-proven): tile 128x32 f16 = 8KB; 256 threads x 2 rounds x 16B.
  const int row0 = tid >> 2, c80 = (tid & 3) << 3;
  const int row1 = (256 + tid) >> 2;
  const long ga0 = (m0 + row0) * (long)K + c80;
  const long ga1 = (m0 + row1) * (long)K + c80;
  const long gb0 = (n0 + row0) * (long)K + c80;
  const long gb1 = (n0 + row1) * (long)K + c80;
  const int la0 = row0 * LDSS + c80;
  const int la1 = row1 * LDSS + c80;

  f32x16 acc[2][2] = {};
  f32x16 accc[2][2] = {};

  const int NT = K / BK;

  f16x8 rAh0, rAh1, rAl0, rAl1, rBh0, rBh1, rBl0, rBl1;

#define LOADR(tt)                                                           \
  do {                                                                      \
    const int k0 = (tt) * BK;                                               \
    rAh0 = *reinterpret_cast<const f16x8*>(Ahi + ga0 + k0);                 \
    rAh1 = *reinterpret_cast<const f16x8*>(Ahi + ga1 + k0);                 \
    rAl0 = *reinterpret_cast<const f16x8*>(Alo + ga0 + k0);                 \
    rAl1 = *reinterpret_cast<const f16x8*>(Alo + ga1 + k0);                 \
    rBh0 = *reinterpret_cast<const f16x8*>(Whi + gb0 + k0);                 \
    rBh1 = *reinterpret_cast<const f16x8*>(Whi + gb1 + k0);                 \
    rBl0 = *reinterpret_cast<const f16x8*>(Wlo + gb0 + k0);                 \
    rBl1 = *reinterpret_cast<const f16x8*>(Wlo + gb1 + k0);                 \
  } while (0)
#define WRITEB(buf)                                                         \
  do {                                                                      \
    *reinterpret_cast<f16x8*>(&sAh[(buf)][la0]) = rAh0;                     \
    *reinterpret_cast<f16x8*>(&sAh[(buf)][la1]) = rAh1;                     \
    *reinterpret_cast<f16x8*>(&sAl[(buf)][la0]) = rAl0;                     \
    *reinterpret_cast<f16x8*>(&sAl[(buf)][la1]) = rAl1;                     \
    *reinterpret_cast<f16x8*>(&sBh[(buf)][la0]) = rBh0;                     \
    *reinterpret_cast<f16x8*>(&sBh[(buf)][la1]) = rBh1;                     \
    *reinterpret_cast<f16x8*>(&sBl[(buf)][la0]) = rBl0;                     \
    *reinterpret_cast<f16x8*>(&sBl[(buf)][la1]) = rBl1;                     \
  } while (0)

  LOADR(0);
  WRITEB(0);
  __syncthreads();

  int cur = 0;
  for (int t = 0; t < NT; ++t) {
    const bool pf = (t + 1) < NT;
    if (pf) LOADR(t + 1);  // issue early; vmcnt wait lands after the MFMA cluster

    __builtin_amdgcn_s_setprio(1);
#pragma unroll
    for (int ks = 0; ks < 2; ++ks) {
      const int ko = ks * 16 + fk32;
      f16x8 ah[2], al[2], bh[2], bl[2];
#pragma unroll
      for (int rb = 0; rb < 2; ++rb) {
        ah[rb] = *reinterpret_cast<const f16x8*>(&sAh[cur][(wm + rb * 32 + fr32) * LDSS + ko]);
        al[rb] = *reinterpret_cast<const f16x8*>(&sAl[cur][(wm + rb * 32 + fr32) * LDSS + ko]);
        bh[rb] = *reinterpret_cast<const f16x8*>(&sBh[cur][(wn + rb * 32 + fr32) * LDSS + ko]);
        bl[rb] = *reinterpret_cast<const f16x8*>(&sBl[cur][(wn + rb * 32 + fr32) * LDSS + ko]);
      }
#pragma unroll
      for (int rb = 0; rb < 2; ++rb)
#pragma unroll
        for (int cb = 0; cb < 2; ++cb) {
          acc[rb][cb] =
              __builtin_amdgcn_mfma_f32_32x32x16_f16(ah[rb], bh[cb], acc[rb][cb], 0, 0, 0);
          accc[rb][cb] =
              __builtin_amdgcn_mfma_f32_32x32x16_f16(ah[rb], bl[cb], accc[rb][cb], 0, 0, 0);
          accc[rb][cb] =
              __builtin_amdgcn_mfma_f32_32x32x16_f16(al[rb], bh[cb], accc[rb][cb], 0, 0, 0);
        }
    }
    __builtin_amdgcn_s_setprio(0);

    if (pf) {
      WRITEB(cur ^ 1);   // compiler inserts vmcnt waits before the ds_writes
      __syncthreads();
      cur ^= 1;
    }
  }
#undef LOADR
#undef WRITEB

  // epilogue: 32x32 C/D map (m74/m101): col = lane&31, row = (reg&3)+8*(reg>>2)+4*(lane>>5)
  const int c32 = lane & 31;
  const int rhi = (lane >> 5) * 4;
#pragma unroll
  for (int cb = 0; cb < 2; ++cb) {
    int gc = n0 + wn + cb * 32 + c32;
    float bv = bias[gc];
#pragma unroll
    for (int rb = 0; rb < 2; ++rb) {
      long grb = m0 + wm + rb * 32;
#pragma unroll
      for (int r = 0; r < 16; ++r) {
        long gr = grb + (r & 3) + 8 * (r >> 2) + rhi;
        P[gr * NCOLS + gc] = acc[rb][cb][r] + accc[rb][cb][r] * (1.0f / 2048.0f) + bv;
      }
    }
  }
}

// ---------- BRC scan over one t-chunk: one thread per (b,h) chain ----------
__global__ __launch_bounds__(256) void scan_kernel(
    const float* __restrict__ P, const float* __restrict__ hinit,
    float* __restrict__ hstate, int first,
    const float* __restrict__ wc, const float* __restrict__ wa,
    f16* __restrict__ Yhi, f16* __restrict__ Ylo,
    float* __restrict__ Yf,
    float* __restrict__ HN) {
  const int j = blockIdx.x * 256 + threadIdx.x;  // 0..65535
  const int hh = j & (HDIM - 1);
  float h = first ? hinit[j] : hstate[j];
  const float wcv = wc[hh];
  const float wav = wa[hh];
  const float* p = P + (long)(j >> 9) * NCOLS + hh;
  long yo = j;
#pragma unroll 8
  for (int t = 0; t < TCHUNK; ++t) {
    float pc = p[0];
    float pa = p[HDIM];
    float ph = p[2 * HDIM];
    float c = fast_sigmoid(fmaf(wcv, h, pc));
    float a = 1.0f + fast_tanh(fmaf(wav, h, pa));
    h = c * h + (1.0f - c) * fast_tanh(fmaf(a, h, ph));
    if (Yhi) {
      f16 hv = (f16)h;
      Yhi[yo] = hv;
      Ylo[yo] = (f16)((h - (float)hv) * 2048.0f);
    }
    if (Yf) Yf[yo] = h;
    yo += BHDIM;
    p += BATCH * NCOLS;
  }
  hstate[j] = h;
  if (HN) HN[j] = h;
}

extern "C" void kernel_launch(void* const* d_in, const int* in_sizes, int n_in,
                              void* d_out, int out_size, void* d_ws, size_t ws_size,
                              hipStream_t stream) {
  const float* x   = (const float*)d_in[0];
  const float* h0  = (const float*)d_in[1];
  const float* Uc0 = (const float*)d_in[2];
  const float* wc0 = (const float*)d_in[3];
  const float* bc0 = (const float*)d_in[4];
  const float* Ua0 = (const float*)d_in[5];
  const float* wa0 = (const float*)d_in[6];
  const float* ba0 = (const float*)d_in[7];
  const float* Uh0 = (const float*)d_in[8];
  const float* bh0 = (const float*)d_in[9];
  const float* Uc1 = (const float*)d_in[10];
  const float* wc1 = (const float*)d_in[11];
  const float* bc1 = (const float*)d_in[12];
  const float* Ua1 = (const float*)d_in[13];
  const float* wa1 = (const float*)d_in[14];
  const float* ba1 = (const float*)d_in[15];
  const float* Uh1 = (const float*)d_in[16];
  const float* bh1 = (const float*)d_in[17];

  if (ws_size < WS_NEEDED) return;

  char* ws = (char*)d_ws;
  float* p32  = (float*)(ws + P32_OFF);
  f16* xhi    = (f16*)(ws + XHI_OFF);
  f16* xlo    = (f16*)(ws + XLO_OFF);
  f16* y0hi   = (f16*)(ws + Y0HI_OFF);
  f16* y0lo   = (f16*)(ws + Y0LO_OFF);
  f16* whi    = (f16*)(ws + WHI_OFF);
  f16* wlo    = (f16*)(ws + WLO_OFF);
  float* bias = (float*)(ws + BIAS_OFF);
  float* hst  = (float*)(ws + HST_OFF);

  float* y1  = (float*)d_out;
  float* hn0 = y1 + (long)SEQ * BHDIM;
  float* hn1 = hn0 + BHDIM;

  const int NCH = SEQ / TCHUNK;  // 8
  const dim3 gemm_grid(CHROWS / 128 * (NCOLS / 128));  // 1536, %8==0

  // ---- prep 0: x split + L0 weight splits + L0 biases (one dispatch) ----
  hipLaunchKernelGGL(prep_kernel, dim3(2048), dim3(256), 0, stream,
                     x, xhi, xlo, MROWS * INDIM / 4,
                     Uc0, Ua0, Uh0, whi, wlo, HDIM * INDIM / 4,
                     bc0, ba0, bh0, bias, HDIM / 4);

  // ---- layer 0: chunked GEMM + scan ----
  for (int tc = 0; tc < NCH; ++tc) {
    hipLaunchKernelGGL(gemm_split_kernel, gemm_grid, dim3(256), 0, stream,
                       xhi + (long)tc * CHROWS * INDIM, xlo + (long)tc * CHROWS * INDIM,
                       whi, wlo, bias, p32, INDIM);
    hipLaunchKernelGGL(scan_kernel, dim3(BHDIM / 256), dim3(256), 0, stream,
                       p32, h0, hst, (tc == 0) ? 1 : 0, wc0, wa0,
                       y0hi + (long)tc * TCHUNK * BHDIM, y0lo + (long)tc * TCHUNK * BHDIM,
                       (float*)nullptr, (tc == NCH - 1) ? hn0 : (float*)nullptr);
  }

  // ---- prep 1: L1 weight splits + L1 biases (one dispatch) ----
  hipLaunchKernelGGL(prep_kernel, dim3(512), dim3(256), 0, stream,
                     (const float*)nullptr, (f16*)nullptr, (f16*)nullptr, 0,
                     Uc1, Ua1, Uh1, whi, wlo, HDIM * HDIM / 4,
                     bc1, ba1, bh1, bias, HDIM / 4);

  // ---- layer 1: chunked GEMM + scan ----
  for (int tc = 0; tc < NCH; ++tc) {
    hipLaunchKernelGGL(gemm_split_kernel, gemm_grid, dim3(256), 0, stream,
                       y0hi + (long)tc * CHROWS * HDIM, y0lo + (long)tc * CHROWS * HDIM,
                       whi, wlo, bias, p32, HDIM);
    hipLaunchKernelGGL(scan_kernel, dim3(BHDIM / 256), dim3(256), 0, stream,
                       p32, h0 + BHDIM, hst, (tc == 0) ? 1 : 0, wc1, wa1,
                       (f16*)nullptr, (f16*)nullptr, y1 + (long)tc * TCHUNK * BHDIM,
                       (tc == NCH - 1) ? hn1 : (float*)nullptr);
  }
}

// Round 13
// 1623.591 us; speedup vs baseline: 1.5200x; 1.5200x over previous
//
#include <hip/hip_runtime.h>
#include <cstdint>
#include <cstddef>

typedef _Float16 f16;
typedef _Float16 f16x4 __attribute__((ext_vector_type(4)));
typedef _Float16 f16x8 __attribute__((ext_vector_type(8)));
typedef float f32x4 __attribute__((ext_vector_type(4)));

// ---------- sizes ----------
#define SEQ 1024
#define BATCH 128
#define INDIM 256
#define HDIM 512
#define MROWS (SEQ * BATCH)          // 131072
#define NCOLS (3 * HDIM)             // 1536
#define BHDIM (BATCH * HDIM)         // 65536
#define TCHUNK 256
#define CHROWS (TCHUNK * BATCH)      // 32768
#define NCH (SEQ / TCHUNK)           // 4

// workspace layout (bytes); total 473,176,064 < 506,730,496 proven available
#define P32_OFF   0ull                         // [32768][1536] f32 = 201,326,592
#define Y0_OFF    201326592ull                 // [131072][512] f32 = 268,435,456
#define WHI_OFF   469762048ull                 // [1536][512] f16   = 1,572,864
#define WLO_OFF   471334912ull                 // [1536][512] f16   = 1,572,864
#define BIAS_OFF  472907776ull                 // [1536] f32        = 6,144
#define HST_OFF   472913920ull                 // [65536] f32       = 262,144
#define WS_NEEDED 473176064ull

__device__ __forceinline__ float fast_tanh(float x) {
  return 1.0f - 2.0f / (__expf(2.0f * x) + 1.0f);
}
__device__ __forceinline__ float fast_sigmoid(float x) {
  return 1.0f / (1.0f + __expf(-x));
}

__device__ __forceinline__ void split4(const float* __restrict__ in, f16* __restrict__ hi,
                                       f16* __restrict__ lo, int i) {
  float4 v = reinterpret_cast<const float4*>(in)[i];
  f16x4 h4 = {(f16)v.x, (f16)v.y, (f16)v.z, (f16)v.w};
  f16x4 l4 = {(f16)((v.x - (float)h4[0]) * 2048.0f),
              (f16)((v.y - (float)h4[1]) * 2048.0f),
              (f16)((v.z - (float)h4[2]) * 2048.0f),
              (f16)((v.w - (float)h4[3]) * 2048.0f)};
  reinterpret_cast<f16x4*>(hi)[i] = h4;
  reinterpret_cast<f16x4*>(lo)[i] = l4;
}

// ---------- consolidated prep: 3 weight splits + 3 bias copies (one dispatch) ----------
__global__ __launch_bounds__(256) void prep_kernel(
    const float* __restrict__ w0, const float* __restrict__ w1, const float* __restrict__ w2,
    f16* __restrict__ wh, f16* __restrict__ wl, int n4w,
    const float* __restrict__ b0, const float* __restrict__ b1, const float* __restrict__ b2,
    float* __restrict__ bias, int nb4) {
  const int total = 3 * n4w + 3 * nb4;
  const int stride = gridDim.x * blockDim.x;
  for (int i = blockIdx.x * blockDim.x + threadIdx.x; i < total; i += stride) {
    if (i < 3 * n4w) {
      int m = i / n4w;
      int off = i - m * n4w;
      const float* src = (m == 0) ? w0 : ((m == 1) ? w1 : w2);
      split4(src, wh + (long)m * n4w * 4, wl + (long)m * n4w * 4, off);
    } else {
      int k = i - 3 * n4w;
      int m = k / nb4;
      int off = k - m * nb4;
      const float* src = (m == 0) ? b0 : ((m == 1) ? b1 : b2);
      reinterpret_cast<float4*>(bias)[m * nb4 + off] =
          reinterpret_cast<const float4*>(src)[off];
    }
  }
}

// ---------- GEMM: P[CHROWS,1536](f32) = (split(A_f32)).(Whi+Wlo/2048)^T + bias ----------
// r9 core (padded conflict-free LDS, T14 reg-staged double buffer, one sync per K-step,
// 16x16x32 MFMA, 4 waves 2x2, 3 MFMA per frag pair) with r2-proven INLINE A-split:
// A is f32 in memory (x or y0 directly); each K-step stages A as 4 float4/thread,
// splits to f16 hi/lo in registers, ds_writes into padded LDS. B weights pre-split.
__global__ __launch_bounds__(256, 2) void gemm_split_kernel(
    const float* __restrict__ A,
    const f16* __restrict__ Whi, const f16* __restrict__ Wlo,
    const float* __restrict__ bias, float* __restrict__ P, int K) {
  constexpr int BK = 32;
  constexpr int LDSS = BK + 8;  // 40 f16 = 80 B row stride (conflict-free reads)
  __shared__ f16 sAh[2][128 * LDSS];
  __shared__ f16 sAl[2][128 * LDSS];
  __shared__ f16 sBh[2][128 * LDSS];
  __shared__ f16 sBl[2][128 * LDSS];

  const int tid = threadIdx.x;
  const int lane = tid & 63;
  const int w = tid >> 6;
  const int wm = (w >> 1) * 64;
  const int wn = (w & 1) * 64;

  // XCD-aware bijective swizzle (gridDim.x = 3072, %8 == 0), n-block fastest
  const int per = gridDim.x >> 3;
  const int logical = (blockIdx.x & 7) * per + (blockIdx.x >> 3);
  const int nb = logical % (NCOLS / 128);
  const int mb = logical / (NCOLS / 128);
  const long m0 = (long)mb * 128;
  const int n0 = nb * 128;

  const int fr = lane & 15;
  const int fk = (lane >> 4) * 8;

  // A staging: 128x32 f32 tile = 4 rounds x 256 threads x 16B (float4).
  // round r: row = r*32 + tid>>3, c4 = (tid&7)*4.
  const int arow = tid >> 3;
  const int ac4 = (tid & 7) << 2;
  // B staging: 128x32 f16 tile per matrix = 2 rounds x 256 x 16B (f16x8).
  const int brow = tid >> 2;
  const int bc8 = (tid & 3) << 3;

  f32x4 acc[4][4] = {};
  f32x4 accc[4][4] = {};

  const int NT = K / BK;

  float4 rA[4];
  f16x8 rBh[2], rBl[2];

#define LOADR(tt)                                                              \
  do {                                                                         \
    const int k0 = (tt) * BK;                                                  \
    _Pragma("unroll")                                                          \
    for (int r = 0; r < 4; ++r)                                                \
      rA[r] = *reinterpret_cast<const float4*>(A + (m0 + r * 32 + arow) * (long)K + k0 + ac4); \
    _Pragma("unroll")                                                          \
    for (int r = 0; r < 2; ++r) {                                              \
      const long gb = (n0 + r * 64 + brow) * (long)K + k0 + bc8;               \
      rBh[r] = *reinterpret_cast<const f16x8*>(Whi + gb);                      \
      rBl[r] = *reinterpret_cast<const f16x8*>(Wlo + gb);                      \
    }                                                                          \
  } while (0)
#define WRITEB(buf)                                                            \
  do {                                                                         \
    _Pragma("unroll")                                                          \
    for (int r = 0; r < 4; ++r) {                                              \
      f16x4 h4 = {(f16)rA[r].x, (f16)rA[r].y, (f16)rA[r].z, (f16)rA[r].w};     \
      f16x4 l4 = {(f16)((rA[r].x - (float)h4[0]) * 2048.0f),                   \
                  (f16)((rA[r].y - (float)h4[1]) * 2048.0f),                   \
                  (f16)((rA[r].z - (float)h4[2]) * 2048.0f),                   \
                  (f16)((rA[r].w - (float)h4[3]) * 2048.0f)};                  \
      *reinterpret_cast<f16x4*>(&sAh[(buf)][(r * 32 + arow) * LDSS + ac4]) = h4; \
      *reinterpret_cast<f16x4*>(&sAl[(buf)][(r * 32 + arow) * LDSS + ac4]) = l4; \
    }                                                                          \
    _Pragma("unroll")                                                          \
    for (int r = 0; r < 2; ++r) {                                              \
      *reinterpret_cast<f16x8*>(&sBh[(buf)][(r * 64 + brow) * LDSS + bc8]) = rBh[r]; \
      *reinterpret_cast<f16x8*>(&sBl[(buf)][(r * 64 + brow) * LDSS + bc8]) = rBl[r]; \
    }                                                                          \
  } while (0)

  LOADR(0);
  WRITEB(0);
  __syncthreads();

  int cur = 0;
  for (int t = 0; t < NT; ++t) {
    const bool pf = (t + 1) < NT;
    if (pf) LOADR(t + 1);  // issue early; vmcnt wait lands after the MFMA cluster

    f16x8 ah[4], al[4], bh[4], bl[4];
#pragma unroll
    for (int i = 0; i < 4; ++i) {
      ah[i] = *reinterpret_cast<const f16x8*>(&sAh[cur][(wm + i * 16 + fr) * LDSS + fk]);
      al[i] = *reinterpret_cast<const f16x8*>(&sAl[cur][(wm + i * 16 + fr) * LDSS + fk]);
      bh[i] = *reinterpret_cast<const f16x8*>(&sBh[cur][(wn + i * 16 + fr) * LDSS + fk]);
      bl[i] = *reinterpret_cast<const f16x8*>(&sBl[cur][(wn + i * 16 + fr) * LDSS + fk]);
    }

    __builtin_amdgcn_s_setprio(1);
#pragma unroll
    for (int i = 0; i < 4; ++i)
#pragma unroll
      for (int j = 0; j < 4; ++j) {
        acc[i][j]  = __builtin_amdgcn_mfma_f32_16x16x32_f16(ah[i], bh[j], acc[i][j], 0, 0, 0);
        accc[i][j] = __builtin_amdgcn_mfma_f32_16x16x32_f16(ah[i], bl[j], accc[i][j], 0, 0, 0);
        accc[i][j] = __builtin_amdgcn_mfma_f32_16x16x32_f16(al[i], bh[j], accc[i][j], 0, 0, 0);
      }
    __builtin_amdgcn_s_setprio(0);

    if (pf) {
      WRITEB(cur ^ 1);   // split in regs + ds_write (vmcnt auto-waited)
      __syncthreads();
      cur ^= 1;
    }
  }
#undef LOADR
#undef WRITEB

  // epilogue: C/D layout col = lane&15, row = (lane>>4)*4 + reg
  const int crow = (lane >> 4) * 4;
  const int ccol = lane & 15;
#pragma unroll
  for (int j = 0; j < 4; ++j) {
    int gc = n0 + wn + j * 16 + ccol;
    float bv = bias[gc];
#pragma unroll
    for (int i = 0; i < 4; ++i) {
      long gr = m0 + wm + i * 16 + crow;
#pragma unroll
      for (int r = 0; r < 4; ++r) {
        P[(gr + r) * NCOLS + gc] = acc[i][j][r] + accc[i][j][r] * (1.0f / 2048.0f) + bv;
      }
    }
  }
}

// ---------- BRC scan over one t-chunk: one thread per (b,h) chain ----------
// Y (and HN) pre-offset by the caller to this chunk's base.
__global__ __launch_bounds__(256) void scan_kernel(
    const float* __restrict__ P, const float* __restrict__ hinit,
    float* __restrict__ hstate, int first,
    const float* __restrict__ wc, const float* __restrict__ wa,
    float* __restrict__ Y, float* __restrict__ HN) {
  const int j = blockIdx.x * 256 + threadIdx.x;  // 0..65535
  const int hh = j & (HDIM - 1);
  float h = first ? hinit[j] : hstate[j];
  const float wcv = wc[hh];
  const float wav = wa[hh];
  const float* p = P + (long)(j >> 9) * NCOLS + hh;
  float* y = Y + j;
#pragma unroll 4
  for (int t = 0; t < TCHUNK; ++t) {
    float pc = p[0];
    float pa = p[HDIM];
    float ph = p[2 * HDIM];
    float c = fast_sigmoid(fmaf(wcv, h, pc));
    float a = 1.0f + fast_tanh(fmaf(wav, h, pa));
    h = c * h + (1.0f - c) * fast_tanh(fmaf(a, h, ph));
    *y = h;
    y += BHDIM;
    p += BATCH * NCOLS;
  }
  hstate[j] = h;
  if (HN) HN[j] = h;
}

extern "C" void kernel_launch(void* const* d_in, const int* in_sizes, int n_in,
                              void* d_out, int out_size, void* d_ws, size_t ws_size,
                              hipStream_t stream) {
  const float* x   = (const float*)d_in[0];
  const float* h0  = (const float*)d_in[1];
  const float* Uc0 = (const float*)d_in[2];
  const float* wc0 = (const float*)d_in[3];
  const float* bc0 = (const float*)d_in[4];
  const float* Ua0 = (const float*)d_in[5];
  const float* wa0 = (const float*)d_in[6];
  const float* ba0 = (const float*)d_in[7];
  const float* Uh0 = (const float*)d_in[8];
  const float* bh0 = (const float*)d_in[9];
  const float* Uc1 = (const float*)d_in[10];
  const float* wc1 = (const float*)d_in[11];
  const float* bc1 = (const float*)d_in[12];
  const float* Ua1 = (const float*)d_in[13];
  const float* wa1 = (const float*)d_in[14];
  const float* ba1 = (const float*)d_in[15];
  const float* Uh1 = (const float*)d_in[16];
  const float* bh1 = (const float*)d_in[17];

  if (ws_size < WS_NEEDED) return;

  char* ws = (char*)d_ws;
  float* p32  = (float*)(ws + P32_OFF);
  float* y0   = (float*)(ws + Y0_OFF);
  f16* whi    = (f16*)(ws + WHI_OFF);
  f16* wlo    = (f16*)(ws + WLO_OFF);
  float* bias = (float*)(ws + BIAS_OFF);
  float* hst  = (float*)(ws + HST_OFF);

  float* y1  = (float*)d_out;
  float* hn0 = y1 + (long)SEQ * BHDIM;
  float* hn1 = hn0 + BHDIM;

  const dim3 gemm_grid((CHROWS / 128) * (NCOLS / 128));  // 256*12 = 3072, %8==0

  // ---- prep 0: L0 weight splits + biases ----
  hipLaunchKernelGGL(prep_kernel, dim3(512), dim3(256), 0, stream,
                     Uc0, Ua0, Uh0, whi, wlo, HDIM * INDIM / 4,
                     bc0, ba0, bh0, bias, HDIM / 4);

  // ---- layer 0: chunked GEMM (A = x f32, inline split) + scan ----
  for (int tc = 0; tc < NCH; ++tc) {
    hipLaunchKernelGGL(gemm_split_kernel, gemm_grid, dim3(256), 0, stream,
                       x + (long)tc * CHROWS * INDIM, whi, wlo, bias, p32, INDIM);
    hipLaunchKernelGGL(scan_kernel, dim3(BHDIM / 256), dim3(256), 0, stream,
                       p32, h0, hst, (tc == 0) ? 1 : 0, wc0, wa0,
                       y0 + (long)tc * TCHUNK * BHDIM,
                       (tc == NCH - 1) ? hn0 : (float*)nullptr);
  }

  // ---- prep 1: L1 weight splits + biases ----
  hipLaunchKernelGGL(prep_kernel, dim3(512), dim3(256), 0, stream,
                     Uc1, Ua1, Uh1, whi, wlo, HDIM * HDIM / 4,
                     bc1, ba1, bh1, bias, HDIM / 4);

  // ---- layer 1: chunked GEMM (A = y0 f32, inline split) + scan ----
  for (int tc = 0; tc < NCH; ++tc) {
    hipLaunchKernelGGL(gemm_split_kernel, gemm_grid, dim3(256), 0, stream,
                       y0 + (long)tc * CHROWS * HDIM, whi, wlo, bias, p32, HDIM);
    hipLaunchKernelGGL(scan_kernel, dim3(BHDIM / 256), dim3(256), 0, stream,
                       p32, h0 + BHDIM, hst, (tc == 0) ? 1 : 0, wc1, wa1,
                       y1 + (long)tc * TCHUNK * BHDIM,
                       (tc == NCH - 1) ? hn1 : (float*)nullptr);
  }
}